// Round 16
// baseline (122.620 us; speedup 1.0000x reference)
//
#include <hip/hip_runtime.h>

#define MD   4
#define B_   4
#define C_   128
#define H_   128
#define W_   256
#define ND   9            // 2*MD+1 displacements per axis
#define NW   9            // waves per block, one per dy
#define XPT  4            // x pixels per lane
#define WQ   64           // W-quarter per block
#define YB   8            // y-rows per block

typedef float float4v __attribute__((ext_vector_type(4)));

// Byte-cut geometry: block = (b, y-oct, W-quarter) -> 8 rows x 64 px.
// 9 waves (one per dy); lanes = 16 x-groups x 4 y-subgroups; each lane
// owns 2 adjacent rows. Unique t2 bytes per output px-col drop ~1.9x vs
// the 2-row/full-W family (16 quarter-rows vs 10 full rows per block).
// Body = proven R11 pattern: direct predicated global window loads,
// clamped-row + zero-scale OOB, no LDS, no barriers.
__global__ __launch_bounds__(NW * 64, 2)
void corr_kernel(const float* __restrict__ t1,
                 const float* __restrict__ t2,
                 float* __restrict__ out) {
    const int tid  = threadIdx.x;
    const int lane = tid & 63;
    const int w    = tid >> 6;                 // wave id == dy
    const int bid  = blockIdx.x;               // 256 blocks = 8 XCD * 32
    const int swz  = (bid & 7) * 32 + (bid >> 3);
    const int xq   = swz & 3;                  // W-quarter
    const int yo   = (swz >> 2) & 15;          // y-oct
    const int b    = swz >> 6;                 // 0..3
    const int y0   = yo * YB;
    const int lx   = lane & 15;                // x-group
    const int ys   = lane >> 4;                // y-subgroup 0..3
    const int x0   = xq * WQ + lx * XPT;       // 0..252
    const int yrA  = y0 + 2 * ys;              // this lane's two rows
    const int yrB  = yrA + 1;
    const int yyA  = yrA + w - MD;             // shifted t2 rows
    const int yyB  = yyA + 1;
    const float scA = (0 <= yyA && yyA < H_) ? (1.0f / (float)C_) : 0.0f;
    const float scB = (0 <= yyB && yyB < H_) ? (1.0f / (float)C_) : 0.0f;
    const int ycA  = yyA < 0 ? 0 : (yyA > H_ - 1 ? H_ - 1 : yyA);
    const int ycB  = yyB < 0 ? 0 : (yyB > H_ - 1 ? H_ - 1 : yyB);
    const bool lm  = (x0 == 0);                // true image edges only
    const bool rm  = (x0 == W_ - XPT);
    const int offL = lm ? 0 : -4;              // clamped halo offsets
    const int offR = rm ? 0 :  4;

    float accA[ND][XPT], accB[ND][XPT];
    #pragma unroll
    for (int dx = 0; dx < ND; ++dx)
        #pragma unroll
        for (int j = 0; j < XPT; ++j) { accA[dx][j] = 0.0f; accB[dx][j] = 0.0f; }

    const size_t chstr = (size_t)H_ * W_;
    const float* p1A = t1 + (((size_t)(b * C_)) * H_ + yrA) * W_ + x0;
    const float* p1B = t1 + (((size_t)(b * C_)) * H_ + yrB) * W_ + x0;
    const float* p2A = t2 + (((size_t)(b * C_)) * H_ + ycA) * W_ + x0;
    const float* p2B = t2 + (((size_t)(b * C_)) * H_ + ycB) * W_ + x0;

    #pragma unroll 2
    for (int c = 0; c < C_; ++c) {
        const size_t co = (size_t)c * chstr;
        const float4v aA = *(const float4v*)(p1A + co);
        const float4v aB = *(const float4v*)(p1B + co);

        float4v wlA = *(const float4v*)(p2A + co + offL);
        const float4v vA = *(const float4v*)(p2A + co);
        float4v wrA = *(const float4v*)(p2A + co + offR);
        float4v wlB = *(const float4v*)(p2B + co + offL);
        const float4v vB = *(const float4v*)(p2B + co);
        float4v wrB = *(const float4v*)(p2B + co + offR);

        #pragma unroll
        for (int q = 0; q < 4; ++q) {
            wlA[q] = lm ? 0.0f : wlA[q];
            wrA[q] = rm ? 0.0f : wrA[q];
            wlB[q] = lm ? 0.0f : wlB[q];
            wrB[q] = rm ? 0.0f : wrB[q];
        }

        float winA[XPT + 2 * MD], winB[XPT + 2 * MD];
        #pragma unroll
        for (int q = 0; q < 4; ++q) {
            winA[q] = wlA[q]; winA[4 + q] = vA[q]; winA[8 + q] = wrA[q];
            winB[q] = wlB[q]; winB[4 + q] = vB[q]; winB[8 + q] = wrB[q];
        }

        #pragma unroll
        for (int dx = 0; dx < ND; ++dx)
            #pragma unroll
            for (int j = 0; j < XPT; ++j) {
                accA[dx][j] = fmaf(aA[j], winA[dx + j], accA[dx][j]);
                accB[dx][j] = fmaf(aB[j], winB[dx + j], accB[dx][j]);
            }
    }

    #pragma unroll
    for (int dx = 0; dx < ND; ++dx) {
        float4v oA, oB;
        #pragma unroll
        for (int j = 0; j < XPT; ++j) {
            oA[j] = accA[dx][j] * scA;
            oB[j] = accB[dx][j] * scB;
        }
        const size_t pl = (size_t)(b * ND * ND) + w * ND + dx;
        *(float4v*)&out[(pl * H_ + yrA) * W_ + x0] = oA;
        *(float4v*)&out[(pl * H_ + yrB) * W_ + x0] = oB;
    }
}

extern "C" void kernel_launch(void* const* d_in, const int* in_sizes, int n_in,
                              void* d_out, int out_size, void* d_ws, size_t ws_size,
                              hipStream_t stream) {
    const float* t1 = (const float*)d_in[0];
    const float* t2 = (const float*)d_in[1];
    float* out      = (float*)d_out;
    corr_kernel<<<dim3(B_ * (H_ / YB) * (W_ / WQ)), NW * 64, 0, stream>>>(t1, t2, out);
}

// Round 17
// 94.509 us; speedup vs baseline: 1.2974x; 1.2974x over previous
//
#include <hip/hip_runtime.h>

#define MD   4
#define B_   4
#define C_   128
#define H_   128
#define W_   256
#define ND   9

typedef float  float4v __attribute__((ext_vector_type(4)));
typedef float  f32x4   __attribute__((ext_vector_type(4)));
typedef short  bf16x8  __attribute__((ext_vector_type(8)));
typedef unsigned int u32;
typedef u32    u32x4   __attribute__((ext_vector_type(4)));

static __device__ __forceinline__ unsigned short f2bf(float f) {
    u32 u = __float_as_uint(f);
    u32 r = (u + 0x7fffu + ((u >> 16) & 1u)) >> 16;   // RNE
    return (unsigned short)r;
}

// ---- pass 1: fp32 [b][c][y][x] -> bf16 ws [tensor][b][y][kc][x][kk32] ----
__global__ __launch_bounds__(256)
void convert_kernel(const float* __restrict__ t1,
                    const float* __restrict__ t2,
                    unsigned short* __restrict__ ws) {
    const int bid = blockIdx.x;            // bits: [1:0]=kc [8:2]=y [10:9]=b [11]=tn
    const int kc  = bid & 3;
    const int y   = (bid >> 2) & (H_ - 1);
    const int b   = (bid >> 9) & 3;
    const int tn  = bid >> 11;
    const float* src = tn ? t2 : t1;
    unsigned short* dst = ws + (size_t)tn * ((size_t)B_ * H_ * 4 * W_ * 32)
                             + ((((size_t)(b * H_ + y)) * 4 + kc) * W_) * 32;
    const int x = threadIdx.x;             // 0..255

    u32 pk[16];
    #pragma unroll
    for (int i = 0; i < 16; ++i) {
        const float f0 = src[((size_t)(b * C_ + kc * 32 + 2 * i    ) * H_ + y) * W_ + x];
        const float f1 = src[((size_t)(b * C_ + kc * 32 + 2 * i + 1) * H_ + y) * W_ + x];
        pk[i] = (u32)f2bf(f0) | ((u32)f2bf(f1) << 16);
    }
    u32x4* po = (u32x4*)(dst + (size_t)x * 32);
    #pragma unroll
    for (int q = 0; q < 4; ++q) {
        u32x4 v;
        #pragma unroll
        for (int j = 0; j < 4; ++j) v[j] = pk[q * 4 + j];
        po[q] = v;
    }
}

// ---- pass 2: banded-Gram MFMA ----
// block=(b,y): 8 waves x 2 x-tiles. Per tile: G-band = 2 MFMA tiles
// (B bases X0-8, X0+8) x 9 yy x 4 k-chunks. Extraction via per-wave
// stride-33 LDS repack (conflict-free), coalesced 16-lane stores.
__global__ __launch_bounds__(512, 2)
void corr_mfma_kernel(const unsigned short* __restrict__ ws,
                      float* __restrict__ out) {
    __shared__ float scr[8][2 * 16 * 33];      // 33792 B, per-wave private

    const int tid = threadIdx.x;
    const int l   = tid & 63;
    const int w   = tid >> 6;                  // 0..7
    const int bid = blockIdx.x;                // 512 = 8 XCD * 64
    const int swz = (bid & 7) * 64 + (bid >> 3);
    const int y   = swz & (H_ - 1);
    const int b   = swz >> 7;
    const int ln  = l & 15;
    const int kg  = l >> 4;                    // 0..3
    const unsigned short* t1w = ws;
    const unsigned short* t2w = ws + (size_t)B_ * H_ * 4 * W_ * 32;
    const float scale = 1.0f / (float)C_;
    const bf16x8 z8 = (bf16x8)(short)0;

    for (int t = 0; t < 2; ++t) {              // sequential x-tiles
        const int X0 = (2 * w + t) * 16;

        f32x4 acc0[ND], acc1[ND];
        #pragma unroll
        for (int r = 0; r < ND; ++r) { acc0[r] = (f32x4)0.0f; acc1[r] = (f32x4)0.0f; }

        int col0 = X0 - 8 + ln;                // B-tile 0 column (this lane)
        int col1 = X0 + 8 + ln;                // B-tile 1 column
        const bool ob0 = col0 < 0;
        const bool ob1 = col1 > W_ - 1;
        col0 = ob0 ? 0 : col0;
        col1 = ob1 ? W_ - 1 : col1;

        #pragma unroll
        for (int kc = 0; kc < 4; ++kc) {
            const unsigned short* a_base =
                t1w + ((((size_t)(b * H_ + y)) * 4 + kc) * W_) * 32;
            const bf16x8 a = *(const bf16x8*)(a_base + (size_t)(X0 + ln) * 32 + kg * 8);
            #pragma unroll
            for (int r = 0; r < ND; ++r) {
                const int row = y + r - MD;    // wave-uniform
                if (0 <= row && row < H_) {
                    const unsigned short* b_base =
                        t2w + ((((size_t)(b * H_ + row)) * 4 + kc) * W_) * 32;
                    bf16x8 b0 = *(const bf16x8*)(b_base + (size_t)col0 * 32 + kg * 8);
                    bf16x8 b1 = *(const bf16x8*)(b_base + (size_t)col1 * 32 + kg * 8);
                    b0 = ob0 ? z8 : b0;        // zero-pad OOB x'
                    b1 = ob1 ? z8 : b1;
                    acc0[r] = __builtin_amdgcn_mfma_f32_16x16x32_bf16(a, b0, acc0[r], 0, 0, 0);
                    acc1[r] = __builtin_amdgcn_mfma_f32_16x16x32_bf16(a, b1, acc1[r], 0, 0, 0);
                }
            }
        }

        float* sw = scr[w];                    // T0 at [m*33+n], T1 at 528+...
        #pragma unroll
        for (int r = 0; r < ND; ++r) {
            const int row = y + r - MD;
            const bool liv = (0 <= row && row < H_);
            // park: lane holds D[m = kg*4+i][n = ln]
            #pragma unroll
            for (int i = 0; i < 4; ++i) {
                sw[(kg * 4 + i) * 33 + ln]       = acc0[r][i];
                sw[528 + (kg * 4 + i) * 33 + ln] = acc1[r][i];
            }
            // read band + store (same-wave LDS; compiler orders via lgkmcnt)
            #pragma unroll
            for (int i = 0; i < 3; ++i) {
                const int dx = i * 4 + kg;
                if (dx < ND) {
                    const int m  = ln;
                    const int md = m + dx;
                    const int idx = (md < 12) ? (m * 33 + md + 4)
                                              : (528 + m * 33 + md - 12);
                    const float v = liv ? sw[idx] * scale : 0.0f;
                    out[((((size_t)b * 81) + r * ND + dx) * H_ + y) * W_ + X0 + m] = v;
                }
            }
        }
    }
}

// ---- fallback: proven 76us scalar kernel (R11) if ws too small ----
__global__ __launch_bounds__(9 * 64, 3)
void corr_fallback(const float* __restrict__ t1,
                   const float* __restrict__ t2,
                   float* __restrict__ out) {
    const int tid  = threadIdx.x;
    const int lane = tid & 63;
    const int w    = tid >> 6;
    const int bid  = blockIdx.x;
    const int swz  = (bid & 7) * 32 + (bid >> 3);
    const int yp   = swz & 63;
    const int b    = swz >> 6;
    const int y0   = yp * 2;
    const int half = lane >> 5;
    const int lx   = lane & 31;
    const int x0   = lx * 8;
    const int yrow = y0 + half;
    const int yy   = yrow + w - MD;
    const bool live = (0 <= yy) && (yy < H_);
    const int  yc  = yy < 0 ? 0 : (yy > H_ - 1 ? H_ - 1 : yy);
    const float sc = live ? (1.0f / (float)C_) : 0.0f;
    const bool lm  = (lx == 0);
    const bool rm  = (lx == 31);
    const int offL = lm ? 0 : -4;
    const int offR = rm ? 0 :  8;

    float acc[ND][8];
    #pragma unroll
    for (int dx = 0; dx < ND; ++dx)
        #pragma unroll
        for (int j = 0; j < 8; ++j) acc[dx][j] = 0.0f;

    const float* p1 = t1 + (((size_t)(b * C_)) * H_ + yrow) * W_ + x0;
    const float* p2 = t2 + (((size_t)(b * C_)) * H_ + yc  ) * W_ + x0;
    const size_t chstr = (size_t)H_ * W_;

    #pragma unroll 2
    for (int c = 0; c < C_; ++c) {
        const float* pc1 = p1 + (size_t)c * chstr;
        const float* pc2 = p2 + (size_t)c * chstr;
        const float4v a0 = *(const float4v*)(pc1);
        const float4v a1 = *(const float4v*)(pc1 + 4);
        float4v wl = *(const float4v*)(pc2 + offL);
        const float4v v0 = *(const float4v*)(pc2);
        const float4v v1 = *(const float4v*)(pc2 + 4);
        float4v wr = *(const float4v*)(pc2 + offR);
        #pragma unroll
        for (int q = 0; q < 4; ++q) {
            wl[q] = lm ? 0.0f : wl[q];
            wr[q] = rm ? 0.0f : wr[q];
        }
        float win[16];
        #pragma unroll
        for (int q = 0; q < 4; ++q) {
            win[q] = wl[q]; win[4 + q] = v0[q];
            win[8 + q] = v1[q]; win[12 + q] = wr[q];
        }
        #pragma unroll
        for (int dx = 0; dx < ND; ++dx)
            #pragma unroll
            for (int j = 0; j < 8; ++j) {
                const float aj = (j < 4) ? a0[j] : a1[j - 4];
                acc[dx][j] = fmaf(aj, win[dx + j], acc[dx][j]);
            }
    }

    #pragma unroll
    for (int dx = 0; dx < ND; ++dx) {
        float4v o0, o1;
        #pragma unroll
        for (int j = 0; j < 4; ++j) {
            o0[j] = acc[dx][j] * sc;
            o1[j] = acc[dx][4 + j] * sc;
        }
        const size_t oidx =
            (((size_t)(b * ND * ND) + w * ND + dx) * H_ + yrow) * W_ + x0;
        *(float4v*)&out[oidx]     = o0;
        *(float4v*)&out[oidx + 4] = o1;
    }
}

extern "C" void kernel_launch(void* const* d_in, const int* in_sizes, int n_in,
                              void* d_out, int out_size, void* d_ws, size_t ws_size,
                              hipStream_t stream) {
    const float* t1 = (const float*)d_in[0];
    const float* t2 = (const float*)d_in[1];
    float* out      = (float*)d_out;
    const size_t need = (size_t)2 * B_ * H_ * 4 * W_ * 32 * sizeof(unsigned short);
    if (ws_size >= need) {
        unsigned short* ws = (unsigned short*)d_ws;
        convert_kernel<<<dim3(2 * B_ * H_ * 4), 256, 0, stream>>>(t1, t2, ws);
        corr_mfma_kernel<<<dim3(B_ * H_), 512, 0, stream>>>(ws, out);
    } else {
        corr_fallback<<<dim3(B_ * H_ / 2), 9 * 64, 0, stream>>>(t1, t2, out);
    }
}

// Round 18
// 84.765 us; speedup vs baseline: 1.4466x; 1.1150x over previous
//
#include <hip/hip_runtime.h>

#define MD   4
#define B_   4
#define C_   128
#define H_   128
#define W_   256
#define ND   9

typedef float  float4v __attribute__((ext_vector_type(4)));
typedef float  f32x4   __attribute__((ext_vector_type(4)));
typedef short  bf16x8  __attribute__((ext_vector_type(8)));
typedef unsigned int u32;
typedef u32    u32x4   __attribute__((ext_vector_type(4)));

static __device__ __forceinline__ unsigned short f2bf(float f) {
    u32 u = __float_as_uint(f);
    u32 r = (u + 0x7fffu + ((u >> 16) & 1u)) >> 16;   // RNE
    return (unsigned short)r;
}

// ---- pass 1: t2 fp32 [b][c][y][x] -> bf16 ws [b][y][kc][x][kk32] ----
// 8 channels/thread, 8 independent coalesced loads; 8192 blocks for deep
// TLP (R17's convert had VGPR=20 / ~2 outstanding loads -> latency-bound).
__global__ __launch_bounds__(256)
void convert_t2(const float* __restrict__ t2,
                unsigned short* __restrict__ ws) {
    const int bid = blockIdx.x;          // [1:0]=ko [3:2]=kc [10:4]=y [12:11]=b
    const int ko  = bid & 3;
    const int kc  = (bid >> 2) & 3;
    const int y   = (bid >> 4) & (H_ - 1);
    const int b   = bid >> 11;
    const int x   = threadIdx.x;         // 0..255
    const float* src =
        t2 + ((size_t)(b * C_ + kc * 32 + ko * 8) * H_ + y) * W_ + x;

    float v[8];
    #pragma unroll
    for (int j = 0; j < 8; ++j) v[j] = src[(size_t)j * H_ * W_];

    u32x4 pk;
    #pragma unroll
    for (int q = 0; q < 4; ++q)
        pk[q] = (u32)f2bf(v[2 * q]) | ((u32)f2bf(v[2 * q + 1]) << 16);

    unsigned short* dst =
        ws + ((((size_t)(b * H_ + y)) * 4 + kc) * W_ + x) * 32 + ko * 8;
    *(u32x4*)dst = pk;
}

// ---- pass 2: banded-Gram MFMA, 1 x-tile per wave ----
// A-fragments read t1 fp32 DIRECTLY (per-kg 16-lane x 4B = full 64B lines)
// and convert in-register; B from bf16 ws. Extraction verbatim from R17
// (passed refcheck): per-wave stride-33 LDS repack, band gather, store.
__global__ __launch_bounds__(512, 4)
void corr_mfma2(const float* __restrict__ t1,
                const unsigned short* __restrict__ ws,
                float* __restrict__ out) {
    __shared__ float scr[8][2 * 16 * 33];      // 33792 B, per-wave private

    const int tid = threadIdx.x;
    const int l   = tid & 63;
    const int w   = tid >> 6;                  // 0..7
    const int bid = blockIdx.x;                // 1024 = 8 XCD * 128
    const int swz = (bid & 7) * 128 + (bid >> 3);
    const int xh  = swz & 1;                   // x-half
    const int y   = (swz >> 1) & (H_ - 1);
    const int b   = swz >> 8;
    const int ln  = l & 15;
    const int kg  = l >> 4;                    // 0..3
    const int X0  = (xh * 8 + w) * 16;         // this wave's x-tile
    const float scale = 1.0f / (float)C_;
    const bf16x8 z8 = (bf16x8)(short)0;

    f32x4 acc0[ND], acc1[ND];
    #pragma unroll
    for (int r = 0; r < ND; ++r) { acc0[r] = (f32x4)0.0f; acc1[r] = (f32x4)0.0f; }

    int col0 = X0 - 8 + ln;                    // B-tile 0 column (this lane)
    int col1 = X0 + 8 + ln;                    // B-tile 1 column
    const bool ob0 = col0 < 0;
    const bool ob1 = col1 > W_ - 1;
    col0 = ob0 ? 0 : col0;
    col1 = ob1 ? W_ - 1 : col1;

    #pragma unroll
    for (int kc = 0; kc < 4; ++kc) {
        // A[m=X0+ln][k=kg*8+j] = t1[b][kc*32+kg*8+j][y][X0+ln], fp32->bf16
        const float* a_src =
            t1 + ((size_t)(b * C_ + kc * 32 + kg * 8) * H_ + y) * W_ + X0 + ln;
        float av[8];
        #pragma unroll
        for (int j = 0; j < 8; ++j) av[j] = a_src[(size_t)j * H_ * W_];
        bf16x8 a;
        #pragma unroll
        for (int j = 0; j < 8; ++j) a[j] = (short)f2bf(av[j]);

        #pragma unroll
        for (int r = 0; r < ND; ++r) {
            const int row = y + r - MD;        // wave-uniform
            if (0 <= row && row < H_) {
                const unsigned short* b_base =
                    ws + ((((size_t)(b * H_ + row)) * 4 + kc) * W_) * 32;
                bf16x8 b0 = *(const bf16x8*)(b_base + (size_t)col0 * 32 + kg * 8);
                bf16x8 b1 = *(const bf16x8*)(b_base + (size_t)col1 * 32 + kg * 8);
                b0 = ob0 ? z8 : b0;            // zero-pad OOB x'
                b1 = ob1 ? z8 : b1;
                acc0[r] = __builtin_amdgcn_mfma_f32_16x16x32_bf16(a, b0, acc0[r], 0, 0, 0);
                acc1[r] = __builtin_amdgcn_mfma_f32_16x16x32_bf16(a, b1, acc1[r], 0, 0, 0);
            }
        }
    }

    float* sw = scr[w];                        // T0 at [m*33+n], T1 at 528+..
    #pragma unroll
    for (int r = 0; r < ND; ++r) {
        const int row = y + r - MD;
        const bool liv = (0 <= row && row < H_);
        // park: lane holds D[m = kg*4+i][n = ln]
        #pragma unroll
        for (int i = 0; i < 4; ++i) {
            sw[(kg * 4 + i) * 33 + ln]       = acc0[r][i];
            sw[528 + (kg * 4 + i) * 33 + ln] = acc1[r][i];
        }
        // read band + store (same-wave LDS; compiler orders via lgkmcnt)
        #pragma unroll
        for (int i = 0; i < 3; ++i) {
            const int dx = i * 4 + kg;
            if (dx < ND) {
                const int m  = ln;
                const int md = m + dx;
                const int idx = (md < 12) ? (m * 33 + md + 4)
                                          : (528 + m * 33 + md - 12);
                const float v = liv ? sw[idx] * scale : 0.0f;
                out[((((size_t)b * 81) + r * ND + dx) * H_ + y) * W_ + X0 + m] = v;
            }
        }
    }
}

// ---- fallback: proven 76us scalar kernel (R11) if ws too small ----
__global__ __launch_bounds__(9 * 64, 3)
void corr_fallback(const float* __restrict__ t1,
                   const float* __restrict__ t2,
                   float* __restrict__ out) {
    const int tid  = threadIdx.x;
    const int lane = tid & 63;
    const int w    = tid >> 6;
    const int bid  = blockIdx.x;
    const int swz  = (bid & 7) * 32 + (bid >> 3);
    const int yp   = swz & 63;
    const int b    = swz >> 6;
    const int y0   = yp * 2;
    const int half = lane >> 5;
    const int lx   = lane & 31;
    const int x0   = lx * 8;
    const int yrow = y0 + half;
    const int yy   = yrow + w - MD;
    const bool live = (0 <= yy) && (yy < H_);
    const int  yc  = yy < 0 ? 0 : (yy > H_ - 1 ? H_ - 1 : yy);
    const float sc = live ? (1.0f / (float)C_) : 0.0f;
    const bool lm  = (lx == 0);
    const bool rm  = (lx == 31);
    const int offL = lm ? 0 : -4;
    const int offR = rm ? 0 :  8;

    float acc[ND][8];
    #pragma unroll
    for (int dx = 0; dx < ND; ++dx)
        #pragma unroll
        for (int j = 0; j < 8; ++j) acc[dx][j] = 0.0f;

    const float* p1 = t1 + (((size_t)(b * C_)) * H_ + yrow) * W_ + x0;
    const float* p2 = t2 + (((size_t)(b * C_)) * H_ + yc  ) * W_ + x0;
    const size_t chstr = (size_t)H_ * W_;

    #pragma unroll 2
    for (int c = 0; c < C_; ++c) {
        const float* pc1 = p1 + (size_t)c * chstr;
        const float* pc2 = p2 + (size_t)c * chstr;
        const float4v a0 = *(const float4v*)(pc1);
        const float4v a1 = *(const float4v*)(pc1 + 4);
        float4v wl = *(const float4v*)(pc2 + offL);
        const float4v v0 = *(const float4v*)(pc2);
        const float4v v1 = *(const float4v*)(pc2 + 4);
        float4v wr = *(const float4v*)(pc2 + offR);
        #pragma unroll
        for (int q = 0; q < 4; ++q) {
            wl[q] = lm ? 0.0f : wl[q];
            wr[q] = rm ? 0.0f : wr[q];
        }
        float win[16];
        #pragma unroll
        for (int q = 0; q < 4; ++q) {
            win[q] = wl[q]; win[4 + q] = v0[q];
            win[8 + q] = v1[q]; win[12 + q] = wr[q];
        }
        #pragma unroll
        for (int dx = 0; dx < ND; ++dx)
            #pragma unroll
            for (int j = 0; j < 8; ++j) {
                const float aj = (j < 4) ? a0[j] : a1[j - 4];
                acc[dx][j] = fmaf(aj, win[dx + j], acc[dx][j]);
            }
    }

    #pragma unroll
    for (int dx = 0; dx < ND; ++dx) {
        float4v o0, o1;
        #pragma unroll
        for (int j = 0; j < 4; ++j) {
            o0[j] = acc[dx][j] * sc;
            o1[j] = acc[dx][4 + j] * sc;
        }
        const size_t oidx =
            (((size_t)(b * ND * ND) + w * ND + dx) * H_ + yrow) * W_ + x0;
        *(float4v*)&out[oidx]     = o0;
        *(float4v*)&out[oidx + 4] = o1;
    }
}

extern "C" void kernel_launch(void* const* d_in, const int* in_sizes, int n_in,
                              void* d_out, int out_size, void* d_ws, size_t ws_size,
                              hipStream_t stream) {
    const float* t1 = (const float*)d_in[0];
    const float* t2 = (const float*)d_in[1];
    float* out      = (float*)d_out;
    const size_t need = (size_t)B_ * H_ * 4 * W_ * 32 * sizeof(unsigned short);
    if (ws_size >= need) {
        unsigned short* ws = (unsigned short*)d_ws;
        convert_t2<<<dim3(4 * B_ * H_ * 4), 256, 0, stream>>>(t2, ws);
        corr_mfma2<<<dim3(2 * B_ * H_), 512, 0, stream>>>(t1, ws, out);
    } else {
        corr_fallback<<<dim3(B_ * H_ / 2), 9 * 64, 0, stream>>>(t1, t2, out);
    }
}

// Round 19
// 64.792 us; speedup vs baseline: 1.8925x; 1.3083x over previous
//
#include <hip/hip_runtime.h>

#define MD   4
#define B_   4
#define C_   128
#define H_   128
#define W_   256
#define ND   9

typedef float  float4v __attribute__((ext_vector_type(4)));
typedef float  f32x4   __attribute__((ext_vector_type(4)));
typedef short  bf16x8  __attribute__((ext_vector_type(8)));
typedef unsigned int u32;
typedef u32    u32x4   __attribute__((ext_vector_type(4)));

static __device__ __forceinline__ unsigned short f2bf(float f) {
    u32 u = __float_as_uint(f);
    u32 r = (u + 0x7fffu + ((u >> 16) & 1u)) >> 16;   // RNE
    return (unsigned short)r;
}

// ---- pass 1: t2 fp32 [b][c][y][x] -> bf16 ws [b][y][kc][x][kk32] ----
// thread = x; 32 fully-unrolled independent strided loads (ILP), 64B
// contiguous packed write per thread. 2048 blocks = 8/CU.
__global__ __launch_bounds__(256, 2)
void convert_t2(const float* __restrict__ t2,
                unsigned short* __restrict__ ws) {
    const int bid = blockIdx.x;          // [1:0]=kc [8:2]=y [10:9]=b
    const int kc  = bid & 3;
    const int y   = (bid >> 2) & (H_ - 1);
    const int b   = bid >> 9;
    const int x   = threadIdx.x;         // 0..255
    const float* src = t2 + ((size_t)(b * C_ + kc * 32) * H_ + y) * W_ + x;
    const size_t hw = (size_t)H_ * W_;

    float f[32];
    #pragma unroll
    for (int k = 0; k < 32; ++k) f[k] = src[(size_t)k * hw];

    unsigned short* dst =
        ws + ((((size_t)(b * H_ + y)) * 4 + kc) * W_ + x) * 32;
    #pragma unroll
    for (int q = 0; q < 4; ++q) {
        u32x4 pk;
        #pragma unroll
        for (int j = 0; j < 4; ++j)
            pk[j] = (u32)f2bf(f[q * 8 + 2 * j]) |
                    ((u32)f2bf(f[q * 8 + 2 * j + 1]) << 16);
        *(u32x4*)(dst + q * 8) = pk;
    }
}

// ---- pass 2: banded-Gram MFMA, y-PAIR per wave ----
// Wave owns one 16-col x-tile for TWO adjacent y rows. 10 staged t2 rows
// feed both: each B-tile load feeds 4 MFMAs (was 2). B-loads/wave 144->80
// per 2 y. Extraction = R18's refcheck-passed code, once per y.
__global__ __launch_bounds__(512, 2)
void corr_mfma3(const float* __restrict__ t1,
                const unsigned short* __restrict__ ws,
                float* __restrict__ out) {
    __shared__ float scr[8][2 * 16 * 33];      // 33792 B, per-wave private

    const int tid = threadIdx.x;
    const int l   = tid & 63;
    const int w   = tid >> 6;                  // 0..7
    const int bid = blockIdx.x;                // 512 = 8 XCD * 64
    const int swz = (bid & 7) * 64 + (bid >> 3);
    const int xh  = swz & 1;                   // x-half
    const int yp  = (swz >> 1) & 63;           // y-pair
    const int b   = swz >> 7;
    const int y0  = yp * 2;
    const int ln  = l & 15;
    const int kg  = l >> 4;                    // 0..3
    const int X0  = (xh * 8 + w) * 16;         // this wave's x-tile
    const float scale = 1.0f / (float)C_;
    const bf16x8 z8 = (bf16x8)(short)0;
    const size_t hw = (size_t)H_ * W_;

    // acc[y-sel][tile][r]: y0 -> A, y1 -> B
    f32x4 aA0[ND], aA1[ND], aB0[ND], aB1[ND];
    #pragma unroll
    for (int r = 0; r < ND; ++r) {
        aA0[r] = (f32x4)0.0f; aA1[r] = (f32x4)0.0f;
        aB0[r] = (f32x4)0.0f; aB1[r] = (f32x4)0.0f;
    }

    int col0 = X0 - 8 + ln;                    // B-tile 0 column (this lane)
    int col1 = X0 + 8 + ln;                    // B-tile 1 column
    const bool ob0 = col0 < 0;
    const bool ob1 = col1 > W_ - 1;
    col0 = ob0 ? 0 : col0;
    col1 = ob1 ? W_ - 1 : col1;

    #pragma unroll
    for (int kc = 0; kc < 4; ++kc) {
        // A fragments (fp32 direct + in-register bf16 pack) for both y
        const float* aspA =
            t1 + ((size_t)(b * C_ + kc * 32 + kg * 8) * H_ + y0) * W_ + X0 + ln;
        const float* aspB = aspA + W_;         // y0+1
        float avA[8], avB[8];
        #pragma unroll
        for (int j = 0; j < 8; ++j) { avA[j] = aspA[(size_t)j * hw]; }
        #pragma unroll
        for (int j = 0; j < 8; ++j) { avB[j] = aspB[(size_t)j * hw]; }
        bf16x8 fA, fB;
        #pragma unroll
        for (int j = 0; j < 8; ++j) { fA[j] = (short)f2bf(avA[j]);
                                      fB[j] = (short)f2bf(avB[j]); }

        #pragma unroll
        for (int r = 0; r < ND + 1; ++r) {     // staged rows y0-4 .. y0+5
            const int row = y0 + r - MD;       // wave-uniform
            if (0 <= row && row < H_) {
                const unsigned short* b_base =
                    ws + ((((size_t)(b * H_ + row)) * 4 + kc) * W_) * 32;
                bf16x8 b0 = *(const bf16x8*)(b_base + (size_t)col0 * 32 + kg * 8);
                bf16x8 b1 = *(const bf16x8*)(b_base + (size_t)col1 * 32 + kg * 8);
                b0 = ob0 ? z8 : b0;            // zero-pad OOB x'
                b1 = ob1 ? z8 : b1;
                if (r < ND) {                  // feeds y0, dy=r
                    aA0[r] = __builtin_amdgcn_mfma_f32_16x16x32_bf16(fA, b0, aA0[r], 0, 0, 0);
                    aA1[r] = __builtin_amdgcn_mfma_f32_16x16x32_bf16(fA, b1, aA1[r], 0, 0, 0);
                }
                if (r >= 1) {                  // feeds y0+1, dy=r-1
                    aB0[r-1] = __builtin_amdgcn_mfma_f32_16x16x32_bf16(fB, b0, aB0[r-1], 0, 0, 0);
                    aB1[r-1] = __builtin_amdgcn_mfma_f32_16x16x32_bf16(fB, b1, aB1[r-1], 0, 0, 0);
                }
            }
        }
    }

    float* sw = scr[w];                        // T0 at [m*33+n], T1 at 528+..

    // ---- extraction pass 1: y0 (acc sets aA0/aA1) ----
    #pragma unroll
    for (int r = 0; r < ND; ++r) {
        const int row = y0 + r - MD;
        const bool liv = (0 <= row && row < H_);
        #pragma unroll
        for (int i = 0; i < 4; ++i) {
            sw[(kg * 4 + i) * 33 + ln]       = aA0[r][i];
            sw[528 + (kg * 4 + i) * 33 + ln] = aA1[r][i];
        }
        #pragma unroll
        for (int i = 0; i < 3; ++i) {
            const int dx = i * 4 + kg;
            if (dx < ND) {
                const int m  = ln;
                const int md = m + dx;
                const int idx = (md < 12) ? (m * 33 + md + 4)
                                          : (528 + m * 33 + md - 12);
                const float v = liv ? sw[idx] * scale : 0.0f;
                out[((((size_t)b * 81) + r * ND + dx) * H_ + y0) * W_ + X0 + m] = v;
            }
        }
    }
    // ---- extraction pass 2: y0+1 (acc sets aB0/aB1) ----
    #pragma unroll
    for (int r = 0; r < ND; ++r) {
        const int row = y0 + 1 + r - MD;
        const bool liv = (0 <= row && row < H_);
        #pragma unroll
        for (int i = 0; i < 4; ++i) {
            sw[(kg * 4 + i) * 33 + ln]       = aB0[r][i];
            sw[528 + (kg * 4 + i) * 33 + ln] = aB1[r][i];
        }
        #pragma unroll
        for (int i = 0; i < 3; ++i) {
            const int dx = i * 4 + kg;
            if (dx < ND) {
                const int m  = ln;
                const int md = m + dx;
                const int idx = (md < 12) ? (m * 33 + md + 4)
                                          : (528 + m * 33 + md - 12);
                const float v = liv ? sw[idx] * scale : 0.0f;
                out[((((size_t)b * 81) + r * ND + dx) * H_ + (y0 + 1)) * W_ + X0 + m] = v;
            }
        }
    }
}

// ---- fallback: proven 76us scalar kernel (R11) if ws too small ----
__global__ __launch_bounds__(9 * 64, 3)
void corr_fallback(const float* __restrict__ t1,
                   const float* __restrict__ t2,
                   float* __restrict__ out) {
    const int tid  = threadIdx.x;
    const int lane = tid & 63;
    const int w    = tid >> 6;
    const int bid  = blockIdx.x;
    const int swz  = (bid & 7) * 32 + (bid >> 3);
    const int yp   = swz & 63;
    const int b    = swz >> 6;
    const int y0   = yp * 2;
    const int half = lane >> 5;
    const int lx   = lane & 31;
    const int x0   = lx * 8;
    const int yrow = y0 + half;
    const int yy   = yrow + w - MD;
    const bool live = (0 <= yy) && (yy < H_);
    const int  yc  = yy < 0 ? 0 : (yy > H_ - 1 ? H_ - 1 : yy);
    const float sc = live ? (1.0f / (float)C_) : 0.0f;
    const bool lm  = (lx == 0);
    const bool rm  = (lx == 31);
    const int offL = lm ? 0 : -4;
    const int offR = rm ? 0 :  8;

    float acc[ND][8];
    #pragma unroll
    for (int dx = 0; dx < ND; ++dx)
        #pragma unroll
        for (int j = 0; j < 8; ++j) acc[dx][j] = 0.0f;

    const float* p1 = t1 + (((size_t)(b * C_)) * H_ + yrow) * W_ + x0;
    const float* p2 = t2 + (((size_t)(b * C_)) * H_ + yc  ) * W_ + x0;
    const size_t chstr = (size_t)H_ * W_;

    #pragma unroll 2
    for (int c = 0; c < C_; ++c) {
        const float* pc1 = p1 + (size_t)c * chstr;
        const float* pc2 = p2 + (size_t)c * chstr;
        const float4v a0 = *(const float4v*)(pc1);
        const float4v a1 = *(const float4v*)(pc1 + 4);
        float4v wl = *(const float4v*)(pc2 + offL);
        const float4v v0 = *(const float4v*)(pc2);
        const float4v v1 = *(const float4v*)(pc2 + 4);
        float4v wr = *(const float4v*)(pc2 + offR);
        #pragma unroll
        for (int q = 0; q < 4; ++q) {
            wl[q] = lm ? 0.0f : wl[q];
            wr[q] = rm ? 0.0f : wr[q];
        }
        float win[16];
        #pragma unroll
        for (int q = 0; q < 4; ++q) {
            win[q] = wl[q]; win[4 + q] = v0[q];
            win[8 + q] = v1[q]; win[12 + q] = wr[q];
        }
        #pragma unroll
        for (int dx = 0; dx < ND; ++dx)
            #pragma unroll
            for (int j = 0; j < 8; ++j) {
                const float aj = (j < 4) ? a0[j] : a1[j - 4];
                acc[dx][j] = fmaf(aj, win[dx + j], acc[dx][j]);
            }
    }

    #pragma unroll
    for (int dx = 0; dx < ND; ++dx) {
        float4v o0, o1;
        #pragma unroll
        for (int j = 0; j < 4; ++j) {
            o0[j] = acc[dx][j] * sc;
            o1[j] = acc[dx][4 + j] * sc;
        }
        const size_t oidx =
            (((size_t)(b * ND * ND) + w * ND + dx) * H_ + yrow) * W_ + x0;
        *(float4v*)&out[oidx]     = o0;
        *(float4v*)&out[oidx + 4] = o1;
    }
}

extern "C" void kernel_launch(void* const* d_in, const int* in_sizes, int n_in,
                              void* d_out, int out_size, void* d_ws, size_t ws_size,
                              hipStream_t stream) {
    const float* t1 = (const float*)d_in[0];
    const float* t2 = (const float*)d_in[1];
    float* out      = (float*)d_out;
    const size_t need = (size_t)B_ * H_ * 4 * W_ * 32 * sizeof(unsigned short);
    if (ws_size >= need) {
        unsigned short* ws = (unsigned short*)d_ws;
        convert_t2<<<dim3(B_ * H_ * 4), 256, 0, stream>>>(t2, ws);
        corr_mfma3<<<dim3(B_ * H_), 512, 0, stream>>>(t1, ws, out);
    } else {
        corr_fallback<<<dim3(B_ * H_ / 2), 9 * 64, 0, stream>>>(t1, t2, out);
    }
}